// Round 8
// baseline (179.694 us; speedup 1.0000x reference)
//
#include <hip/hip_runtime.h>
#include <stdint.h>

// GateDotProductAttention: B=8,S=2048,D=256 fp32 in/out.
// prep: K,V -> bf16 images in exact 32x32x16-MFMA fragment order; W -> bf16 swizzled chunks.
// attn: bidirectional flash, no-max softmax, 32x32x16 MFMAs, waves=(qh,jh,dh) with QK dup
//       across dh pair; P repacked in-register (pk2 + permlane32_swap); V B-frags direct
//       from L2 (no LDS); K staged via linear global_load_lds; fused gate GEMM epilogue.

typedef unsigned short u16;
typedef unsigned int u32;
typedef __attribute__((ext_vector_type(8))) short short8;
typedef __attribute__((ext_vector_type(4))) float f32x4;
typedef __attribute__((ext_vector_type(16))) float f32x16;

#define B_ 8
#define S_ 2048
#define D_ 256
#define NP 32            // periods of 64 j-rows

#define LOG2E 1.44269504088896340736f
#define QSCALE (LOG2E/16.0f)

#define KIMG_OFF 0u          // 8MB: [b][jb 0..63] 16KB tiles, frag order (ks*64+lane)*16
#define VIMG_OFF (8u<<20)    // 8MB: [b][jb] 16KB tiles, frag order ((db*2+ks2)*64+lane)*16
#define WBF_OFF  (16u<<20)   // 512KB: (db*4+m) 8KB swizzled slices

__device__ __forceinline__ u16 f2bf(float f) {
    union { float f; u32 u; } x; x.f = f;
    u32 u = x.u + 0x7fffu + ((x.u >> 16) & 1u);   // RNE
    return (u16)(u >> 16);
}
__device__ __forceinline__ short8 pack8(float4 a, float4 b) {
    short8 r;
    r[0] = (short)f2bf(a.x); r[1] = (short)f2bf(a.y);
    r[2] = (short)f2bf(a.z); r[3] = (short)f2bf(a.w);
    r[4] = (short)f2bf(b.x); r[5] = (short)f2bf(b.y);
    r[6] = (short)f2bf(b.z); r[7] = (short)f2bf(b.w);
    return r;
}
__device__ __forceinline__ f32x4 mfma16(short8 a, short8 b, f32x4 c) {
    return __builtin_amdgcn_mfma_f32_16x16x32_bf16(a, b, c, 0, 0, 0);
}
__device__ __forceinline__ f32x16 mfma32(short8 a, short8 b, f32x16 c) {
    return __builtin_amdgcn_mfma_f32_32x32x16_bf16(a, b, c, 0, 0, 0);
}
__device__ __forceinline__ u32 pk2(float a, float b) {
    u32 w;
    asm("v_cvt_pk_bf16_f32 %0, %1, %2" : "=v"(w) : "v"(a), "v"(b));
    return w;
}
// v_permlane32_swap_b32: a[32+i] <- b_old[i]; b[i] <- a_old[32+i]
__device__ __forceinline__ void plswap(u32& a, u32& b) {
    asm volatile("v_permlane32_swap_b32 %0, %1" : "+v"(a), "+v"(b));
}
__device__ __forceinline__ void gload_lds(const void* g, void* lds) {
    __builtin_amdgcn_global_load_lds(
        (const __attribute__((address_space(1))) void*)g,
        (__attribute__((address_space(3))) void*)lds, 16, 0, 0);
}

// ---------------------------------------------------------------- prep ----
__global__ __launch_bounds__(256, 1)
void prep_kernel(const float* __restrict__ k, const float* __restrict__ v,
                 const float* __restrict__ w0, const float* __restrict__ w1,
                 const float* __restrict__ w2, const float* __restrict__ w3,
                 char* __restrict__ ws)
{
    const int tid = (int)threadIdx.x;
    const int bid = (int)blockIdx.x;

    if (bid < 1024) {
        // K or V fragment-order tile for (b, jb): stage 32x256 f32 in LDS, gather-emit.
        __shared__ float st[32][264];
        const bool isV = (bid < 512);
        const int t = isV ? bid : bid - 512;
        const int b = t >> 6, jb = t & 63;
        const float* src = (isV ? v : k) + ((size_t)b * S_ + (size_t)jb * 32) * D_;
        const int jr = tid >> 3, d0 = (tid & 7) * 32;
        #pragma unroll
        for (int i = 0; i < 8; ++i) {
            float4 x = *(const float4*)(src + (size_t)jr * D_ + d0 + i * 4);
            *(float4*)&st[jr][d0 + i * 4] = x;
        }
        __syncthreads();
        char* ob = ws + (isV ? VIMG_OFF : KIMG_OFF)
                 + ((size_t)b * 64 + jb) * 16384;
        #pragma unroll
        for (int it = 0; it < 4; ++it) {
            int e = it * 256 + tid;           // entry 0..1023
            int fi = e >> 6, l = e & 63;
            short8 o;
            if (isV) {
                // V B-frag: k=j axis on rows, n=d on lane: V[ks2*16+8*(l>>5)+i][db*32+(l&31)]
                int db = fi >> 1, ks2 = fi & 1;
                int row = ks2 * 16 + (l >> 5) * 8, col = db * 32 + (l & 31);
                #pragma unroll
                for (int i = 0; i < 8; ++i) o[i] = (short)f2bf(st[row + i][col]);
            } else {
                // K A-frag: m=j on lane, k on 8-chunk: K[(l&31)][ks*16+8*(l>>5)+i]
                int ks = fi;
                int row = l & 31, col = ks * 16 + (l >> 5) * 8;
                #pragma unroll
                for (int i = 0; i < 8; ++i) o[i] = (short)f2bf(st[row][col + i]);
            }
            *(short8*)(ob + e * 16) = o;
        }
    } else {
        // W slice (m, db): 16 rows x 256 cols -> swizzled bf16, chunk order (db*4+m)
        const int t = bid - 1024, m = t >> 4, db = t & 15;
        const float* wsrc = (m == 0 ? w0 : m == 1 ? w1 : m == 2 ? w2 : w3)
                            + (size_t)(db * 16) * D_;
        char* ob = ws + WBF_OFF + (size_t)(db * 4 + m) * 8192;
        #pragma unroll
        for (int it = 0; it < 2; ++it) {
            int gi = tid + it * 256;
            int r = gi >> 5, cg = gi & 31;
            float4 x0 = *(const float4*)(wsrc + (size_t)r * D_ + cg * 8);
            float4 x1 = *(const float4*)(wsrc + (size_t)r * D_ + cg * 8 + 4);
            *(short8*)(ob + r * 512 + ((cg * 16) ^ ((r & 7) << 4))) = pack8(x0, x1);
        }
    }
}

// ---------------------------------------------------------------- attn ----
union PaU { u32 w[4]; short8 s; };

__global__ __launch_bounds__(512, 2)
void attn_kernel(const float* __restrict__ q, const char* __restrict__ kimg,
                 const char* __restrict__ vimg, const char* __restrict__ wbf,
                 const float* __restrict__ v,
                 const float* __restrict__ bo0, const float* __restrict__ bo1,
                 float* __restrict__ out)
{
    __shared__ char smem[133632];

    const int tid = (int)threadIdx.x;
    const int wv = tid >> 6, lane = tid & 63;
    const int qh = wv & 1, jh = (wv >> 1) & 1, dh = wv >> 2;
    const int h = lane >> 5, ln = lane & 31;
    const int g = (lane & 63) >> 4, c = lane & 15;   // gate-phase decomposition
    const int bid = (int)blockIdx.x;
    const int b = bid & 7, qi = bid >> 3;
    const int q0 = qi * 64;
    const int qb = qi * 2 + qh;            // this wave's 32-row q block index
    const int qg = q0 + qh * 32 + ln;      // lane's q (lane axis of C)

    const char* kbaseg = kimg + ((size_t)b << 20);
    const char* vbaseg = vimg + ((size_t)b << 20);

    // Q B-frags, pre-scaled: B[k][n=q]: lane ln = q col, k-chunk = 8h
    short8 qf[16];
    {
        const float* qp = q + ((size_t)b * S_ + (size_t)(q0 + qh * 32 + ln)) * D_ + h * 8;
        #pragma unroll
        for (int ks = 0; ks < 16; ++ks) {
            float4 a = *(const float4*)(qp + ks * 16);
            float4 d = *(const float4*)(qp + ks * 16 + 4);
            a.x *= QSCALE; a.y *= QSCALE; a.z *= QSCALE; a.w *= QSCALE;
            d.x *= QSCALE; d.y *= QSCALE; d.z *= QSCALE; d.w *= QSCALE;
            qf[ks] = pack8(a, d);
        }
    }

    f32x16 accF[4] = {}, accB[4] = {};
    float sF = 0.0f, sB = 0.0f;

    #define STAGE_K(t, buf)                                                    \
        {                                                                      \
            const char* kg_ = kbaseg + (size_t)(t) * 32768;                    \
            _Pragma("unroll")                                                  \
            for (int i = 0; i < 4; ++i) {                                      \
                int off = i * 8192 + wv * 1024;                                \
                gload_lds(kg_ + off + lane * 16, smem + (buf) * 32768 + off);  \
            }                                                                  \
        }

    STAGE_K(0, 0);
    __syncthreads();

    #define PVALL(pa0_, pa1_, acc_)                                            \
        {                                                                      \
            __builtin_amdgcn_s_setprio(1);                                     \
            acc_[0] = mfma32(pa0_, vb0a, acc_[0]);                             \
            acc_[0] = mfma32(pa1_, vb0b, acc_[0]);                             \
            acc_[1] = mfma32(pa0_, vb1a, acc_[1]);                             \
            acc_[1] = mfma32(pa1_, vb1b, acc_[1]);                             \
            acc_[2] = mfma32(pa0_, vb2a, acc_[2]);                             \
            acc_[2] = mfma32(pa1_, vb2b, acc_[2]);                             \
            acc_[3] = mfma32(pa0_, vb3a, acc_[3]);                             \
            acc_[3] = mfma32(pa1_, vb3b, acc_[3]);                             \
            __builtin_amdgcn_s_setprio(0);                                     \
        }

    // repack 16 masked/exp'd f32 e[] (j = (r&3)+8*(r>>2)+4h) -> two PV A-frags
    #define REPACK(e_, pa0_, pa1_)                                             \
        {                                                                      \
            u32 w0 = pk2(e_[0], e_[1]),  w1 = pk2(e_[2], e_[3]);               \
            u32 w2 = pk2(e_[4], e_[5]),  w3 = pk2(e_[6], e_[7]);               \
            u32 w4 = pk2(e_[8], e_[9]),  w5 = pk2(e_[10], e_[11]);             \
            u32 w6 = pk2(e_[12], e_[13]), w7 = pk2(e_[14], e_[15]);            \
            plswap(w0, w2); plswap(w1, w3); plswap(w4, w6); plswap(w5, w7);    \
            PaU u0_; u0_.w[0] = w0; u0_.w[1] = w1; u0_.w[2] = w2; u0_.w[3] = w3; \
            PaU u1_; u1_.w[0] = w4; u1_.w[1] = w5; u1_.w[2] = w6; u1_.w[3] = w7; \
            pa0_ = u0_.s; pa1_ = u1_.s;                                        \
        }

    #define SUM16(e_) ((((e_[0]+e_[1])+(e_[2]+e_[3]))+((e_[4]+e_[5])+(e_[6]+e_[7]))) + \
                       (((e_[8]+e_[9])+(e_[10]+e_[11]))+((e_[12]+e_[13])+(e_[14]+e_[15]))))

    #pragma unroll 1
    for (int t = 0; t < NP; ++t) {
        const int cur = t & 1;
        if (t + 1 < NP) STAGE_K(t + 1, cur ^ 1);

        const int jbg = 2 * t + jh;
        const char* vg = vbaseg + (size_t)jbg * 16384 + dh * 8192 + lane * 16;

        // V B-frags for our d-half (L2-resident ws, coalesced 1KB per frag)
        short8 vb0a = *(const short8*)(vg);
        short8 vb0b = *(const short8*)(vg + 1024);
        short8 vb1a = *(const short8*)(vg + 2048);
        short8 vb1b = *(const short8*)(vg + 3072);

        // QK^T swapped: C[m=j][n=q], A = K frags (LDS, frag-linear), B = Q regs
        const char* kc_ = smem + cur * 32768 + jh * 16384 + lane * 16;
        f32x16 sc = {};
        __builtin_amdgcn_s_setprio(1);
        #pragma unroll
        for (int ks = 0; ks < 16; ++ks) {
            short8 kb = *(const short8*)(kc_ + ks * 1024);
            sc = mfma32(kb, qf[ks], sc);
        }
        __builtin_amdgcn_s_setprio(0);

        short8 vb2a = *(const short8*)(vg + 4096);
        short8 vb2b = *(const short8*)(vg + 5120);
        short8 vb3a = *(const short8*)(vg + 6144);
        short8 vb3b = *(const short8*)(vg + 7168);

        #pragma unroll
        for (int i = 0; i < 16; ++i) sc[i] = exp2f(sc[i]);

        if (jbg != qb) {
            float e[16];
            #pragma unroll
            for (int i = 0; i < 16; ++i) e[i] = sc[i];
            short8 pa0, pa1;
            REPACK(e, pa0, pa1);
            float ts = SUM16(e);
            if (jbg < qb) { sB += ts; PVALL(pa0, pa1, accB); }
            else          { sF += ts; PVALL(pa0, pa1, accF); }
        } else {
            // diagonal: both directions, sequential to cap register pressure
            const int jb32 = jbg * 32;
            {
                float e[16];
                #pragma unroll
                for (int r = 0; r < 16; ++r) {
                    int jg = jb32 + (r & 3) + 8 * (r >> 2) + 4 * h;
                    e[r] = (jg <= qg) ? sc[r] : 0.0f;     // bw: j <= q
                }
                short8 pa0, pa1;
                REPACK(e, pa0, pa1);
                sB += SUM16(e);
                PVALL(pa0, pa1, accB);
            }
            {
                float e[16];
                #pragma unroll
                for (int r = 0; r < 16; ++r) {
                    int jg = jb32 + (r & 3) + 8 * (r >> 2) + 4 * h;
                    e[r] = (jg >= qg) ? sc[r] : 0.0f;     // fw: j >= q
                }
                short8 pa0, pa1;
                REPACK(e, pa0, pa1);
                sF += SUM16(e);
                PVALL(pa0, pa1, accF);
            }
        }
        __syncthreads();
    }

    // ---- epilogue ----
    // P0: jh=1 writes accF partial -> F region; jh=0 writes accB -> B region.
    {
        float* dst = (float*)(smem + (jh ? 0 : 65536)) + (qh * 2 + dh) * 4096;
        #pragma unroll
        for (int db = 0; db < 4; ++db)
            #pragma unroll
            for (int r = 0; r < 16; ++r)
                dst[(db * 16 + r) * 64 + lane] = jh ? accF[db][r] : accB[db][r];
        if (dh == 0) {
            ((float*)(smem + 131072))[(qh * 2 + jh) * 64 + lane] = sF;
            ((float*)(smem + 132096))[(qh * 2 + jh) * 64 + lane] = sB;
        }
    }
    __syncthreads();

    // P1: merge partner's partial; one wave per qh computes reciprocal sums.
    {
        const float* src = (const float*)(smem + (jh ? 65536 : 0)) + (qh * 2 + dh) * 4096;
        #pragma unroll
        for (int db = 0; db < 4; ++db)
            #pragma unroll
            for (int r = 0; r < 16; ++r) {
                float p = src[(db * 16 + r) * 64 + lane];
                if (jh) accB[db][r] += p; else accF[db][r] += p;
            }
        if (jh == 0 && dh == 0) {
            const float* pf = (const float*)(smem + (h ? 132096 : 131072));
            int qq = ln;
            float s = pf[(qh * 2 + 0) * 64 + qq] + pf[(qh * 2 + 0) * 64 + 32 + qq]
                    + pf[(qh * 2 + 1) * 64 + qq] + pf[(qh * 2 + 1) * 64 + 32 + qq];
            ((float*)(smem + 133120))[h * 64 + qh * 32 + qq] = 1.0f / s;
        }
    }
    __syncthreads();

    // P2: normalize + write att image (jh=0 -> F @[0,32K), jh=1 -> B @[32K,64K)); stage W chunk 0
    {
        const float* rsp = (const float*)(smem + 133120) + jh * 64;
        char* imgb = smem + jh * 32768;
        #pragma unroll
        for (int db = 0; db < 4; ++db)
            #pragma unroll
            for (int r = 0; r < 16; ++r) {
                int qib = (r & 3) + 8 * (r >> 2) + 4 * h;       // q within 32-block
                float m = (jh ? accB[db][r] : accF[db][r]) * rsp[qh * 32 + qib];
                int row = qh * 32 + qib;
                int dcol = dh * 128 + db * 32 + ln;
                *(u16*)(imgb + row * 512 + ((2 * dcol) ^ ((row & 7) << 4))) = f2bf(m);
            }
    }
    #define WSTAGE(db, buf)                                                    \
        {                                                                      \
            const char* gsrc = wbf + (size_t)(db) * 32768;                     \
            _Pragma("unroll")                                                  \
            for (int i = 0; i < 4; ++i) {                                      \
                int off = i * 8192 + wv * 1024;                                \
                gload_lds(gsrc + off + lane * 16,                              \
                          smem + 65536 + (buf) * 32768 + off);                 \
            }                                                                  \
        }
    WSTAGE(0, 0);
    __syncthreads();

    // P3: gate phase. roles: dir = jh, row group wl2 = qh*2+dh (16 rows each).
    const int wl2 = qh * 2 + dh;
    const int swz = (c & 7) << 4;
    short8 af[8], vf[8];
    {
        const char* imgb = smem + jh * 32768;
        int lr = wl2 * 16 + c;
        #pragma unroll
        for (int ks = 0; ks < 8; ++ks) {
            int inner = (ks * 64 + g * 16) ^ ((lr & 7) << 4);
            af[ks] = *(const short8*)(imgb + lr * 512 + inner);
        }
        const float* vp = v + ((size_t)b * S_ + (size_t)(q0 + wl2 * 16 + c)) * D_;
        #pragma unroll
        for (int ks = 0; ks < 8; ++ks) {
            float4 a = *(const float4*)(vp + ks * 32 + g * 8);
            float4 d = *(const float4*)(vp + ks * 32 + g * 8 + 4);
            vf[ks] = pack8(a, d);
        }
    }

    const float* bias = jh ? bo1 : bo0;
    const float* vrow = v + ((size_t)b * S_ + (size_t)(q0 + wl2 * 16)) * D_;
    const char* imgb2 = smem + jh * 32768;
    float* ob = out + ((size_t)b * S_ + (size_t)(q0 + wl2 * 16)) * 512 + jh * 256;
    #pragma unroll
    for (int db = 0; db < 16; ++db) {
        const int cu2 = db & 1;
        if (db + 1 < 16) WSTAGE(db + 1, cu2 ^ 1);

        float bb = bias[db * 16 + c];
        f32x4 a = {bb, bb, bb, bb};
        const char* wc = smem + 65536 + cu2 * 32768 + jh * 16384;
        __builtin_amdgcn_s_setprio(1);
        #pragma unroll
        for (int ks = 0; ks < 8; ++ks) {
            int inner = (ks * 64 + g * 16) ^ swz;
            short8 wi = *(const short8*)(wc + c * 512 + inner);
            short8 wo = *(const short8*)(wc + 8192 + c * 512 + inner);
            a = mfma16(vf[ks], wi, a);
            a = mfma16(af[ks], wo, a);
        }
        __builtin_amdgcn_s_setprio(0);

        #pragma unroll
        for (int r = 0; r < 4; ++r) {
            int row = wl2 * 16 + g * 4 + r;
            int cc = db * 16 + c;
            float vv = vrow[(size_t)(g * 4 + r) * D_ + cc];
            u32 mu = *(const u16*)(imgb2 + row * 512 + ((2 * cc) ^ ((row & 7) << 4)));
            union { u32 u; float f; } cv; cv.u = mu << 16;
            float gate = 1.0f / (1.0f + exp2f(-a[r] * LOG2E));
            ob[(size_t)(g * 4 + r) * 512 + cc] = gate * cv.f + (1.0f - gate) * vv;
        }
        __syncthreads();
    }
}

extern "C" void kernel_launch(void* const* d_in, const int* in_sizes, int n_in,
                              void* d_out, int out_size, void* d_ws, size_t ws_size,
                              hipStream_t stream)
{
    const float* q   = (const float*)d_in[0];
    const float* k   = (const float*)d_in[1];
    const float* v   = (const float*)d_in[2];
    const float* Wi0 = (const float*)d_in[3];
    const float* Wi1 = (const float*)d_in[4];
    const float* Wo0 = (const float*)d_in[5];
    const float* Wo1 = (const float*)d_in[6];
    const float* bo0 = (const float*)d_in[7];
    const float* bo1 = (const float*)d_in[8];
    float* out = (float*)d_out;
    char* ws = (char*)d_ws;
    (void)in_sizes; (void)n_in; (void)ws_size; (void)out_size;

    prep_kernel<<<dim3(1088), dim3(256), 0, stream>>>(k, v, Wi0, Wo0, Wi1, Wo1, ws);
    attn_kernel<<<dim3(256), dim3(512), 0, stream>>>(q, ws + KIMG_OFF, ws + VIMG_OFF,
                                                     ws + WBF_OFF, v, bo0, bo1, out);
}